// Round 10
// baseline (241.047 us; speedup 1.0000x reference)
//
#include <hip/hip_runtime.h>

#define NN 50000      // nodes
#define NE 800000     // edges
#define F  64         // feature dim
#define AT 68         // padded LDS stride (mult of 4, not mult of 32)
#define SCAN_B 49     // scan blocks: 49 * 1024 >= 50000

// bf16 round-to-nearest-even, returns low-16 bits
__device__ __forceinline__ unsigned bf16rne(float f) {
    unsigned u = __float_as_uint(f);
    return (u + 0x7fffu + ((u >> 16) & 1u)) >> 16;
}
__device__ __forceinline__ float bflo(unsigned p) { return __uint_as_float(p << 16); }
__device__ __forceinline__ float bfhi(unsigned p) { return __uint_as_float(p & 0xffff0000u); }

// ---------------- fused: edge degree count+slot  AND  embedding gather ----------------

__launch_bounds__(256)
__global__ void k_count_gather(const int* __restrict__ dst, int* __restrict__ cnt,
                               int* __restrict__ pos,
                               const float* __restrict__ embed, const int* __restrict__ ids,
                               uint2* __restrict__ xb) {
    int t = blockIdx.x * blockDim.x + threadIdx.x;
    if (t < NE) pos[t] = atomicAdd(&cnt[dst[t]], 1);   // coalesced pos write
    if (t < NN * 16) {
        int i = t >> 4, c = t & 15;
        float4 v = ((const float4*)embed)[ids[i] * 16 + c];
        uint2 p;
        p.x = bf16rne(v.x) | (bf16rne(v.y) << 16);
        p.y = bf16rne(v.z) | (bf16rne(v.w) << 16);
        xb[t] = p;
    }
}

// ---- 2-dispatch scan: block partials, then per-block redundant scan of partials ----

__launch_bounds__(256)
__global__ void k_scan_a(const int* __restrict__ cnt, int* __restrict__ partials) {
    __shared__ int sc[256];
    int t = threadIdx.x;
    int base = blockIdx.x * 1024 + t * 4;
    int s = 0;
#pragma unroll
    for (int k = 0; k < 4; ++k) {
        int idx = base + k;
        s += (idx < NN) ? cnt[idx] : 0;
    }
    sc[t] = s;
    __syncthreads();
    for (int d = 128; d > 0; d >>= 1) {
        if (t < d) sc[t] += sc[t + d];
        __syncthreads();
    }
    if (t == 0) partials[blockIdx.x] = sc[0];
}

__launch_bounds__(256)
__global__ void k_scan_c2(const int* __restrict__ cnt, const int* __restrict__ partials,
                          int* __restrict__ offs) {
    __shared__ int sboff;
    __shared__ int stotal;
    __shared__ int sc[256];
    int t = threadIdx.x;
    if (t < 64) {  // wave 0 redundantly scans the 49 partials
        int v = (t < SCAN_B) ? partials[t] : 0;
        int orig = v;
        for (int d = 1; d < 64; d <<= 1) {
            int u = __shfl_up(v, d);
            if (t >= d) v += u;
        }
        if (t == (int)blockIdx.x) sboff = v - orig;
        if (t == 63) stotal = v;
    }
    int base = blockIdx.x * 1024 + t * 4;
    int v4[4];
#pragma unroll
    for (int k = 0; k < 4; ++k) {
        int idx = base + k;
        v4[k] = (idx < NN) ? cnt[idx] : 0;
    }
    int lsum = v4[0] + v4[1] + v4[2] + v4[3];
    sc[t] = lsum;
    __syncthreads();
    for (int d = 1; d < 256; d <<= 1) {
        int u = (t >= d) ? sc[t - d] : 0;
        __syncthreads();
        sc[t] += u;
        __syncthreads();
    }
    int run = sboff + sc[t] - lsum;
#pragma unroll
    for (int k = 0; k < 4; ++k) {
        int idx = base + k;
        if (idx < NN) { offs[idx] = run; run += v4[k]; }
    }
    if (blockIdx.x == 0 && t == 0) offs[NN] = stotal;
}

// atomic-free fill: slot was precomputed in pos[]
__global__ void k_fill(const int* __restrict__ src, const int* __restrict__ dst,
                       const int* __restrict__ offs, const int* __restrict__ pos,
                       int* __restrict__ csr) {
    int e = blockIdx.x * blockDim.x + threadIdx.x;
    if (e < NE) csr[offs[dst[e]] + pos[e]] = src[e];
}

// ---------------- fused layer: aggregate + GEMM in one kernel ----------------
// 512 threads, 64 nodes/block. Aggregation is FEATURE-SPLIT into two 32-feat
// halves so the gather working set is 3.2 MB (< 4 MB per-XCD L2): per node,
// 8 lanes = 4 chunks x 2 edge-parities; each parity gathers 4 edges/round;
// partial sums combined via shfl_xor(4). N-tile lands in LDS fp32 (no global
// round-trip). Weights Ws|Wn bf16-packed in one LDS array. LDS = 51.2 KB.
// LAST=false: relu -> bf16 out. LAST=true: second GEMM with Wfc/bfc -> fp32 out.

__device__ __forceinline__ void add8(float s[8], const uint4 v) {
    s[0] += bflo(v.x); s[1] += bfhi(v.x);
    s[2] += bflo(v.y); s[3] += bfhi(v.y);
    s[4] += bflo(v.z); s[5] += bfhi(v.z);
    s[6] += bflo(v.w); s[7] += bfhi(v.w);
}

template <bool LAST>
__launch_bounds__(512)
__global__ void k_fused(const uint4* __restrict__ Ab, const int* __restrict__ offs,
                        const int* __restrict__ csr,
                        const float* __restrict__ Ws, const float* __restrict__ Wn,
                        const float* __restrict__ b,
                        const float* __restrict__ Wfc, const float* __restrict__ bfc,
                        uint2* __restrict__ outb, float* __restrict__ out) {
    __shared__ alignas(16) float AsT[F * AT];      // self tile, transposed [f][node]
    __shared__ alignas(16) float NsT[F * AT];      // neighbor-mean tile, transposed
    __shared__ alignas(16) unsigned Wpk[F * F];    // Ws|Wn<<16 bf16-packed [k][f]

    const int tid = threadIdx.x;
    const int node0 = blockIdx.x * 64;

    // stage packed weights
    for (int i = tid; i < F * F; i += 512)
        Wpk[i] = bf16rne(Ws[i]) | (bf16rne(Wn[i]) << 16);

    // ---- A-stage + feature-split aggregation ----
    {
        const int n = tid >> 3;          // node within tile
        const int cc = tid & 7;          // full-row uint4 chunk (A-stage) / lane role
        const int c = cc & 3;            // chunk within current half
        const int p = cc >> 2;           // edge parity
        const int lane = tid & 63;
        const int base = lane & 56;      // first lane of this node's 8-lane group
        const int gnode = node0 + n;

        // self row (full 128 B), unpack to AsT
        uint4 a = make_uint4(0u, 0u, 0u, 0u);
        int beg = 0, end = 0;
        float inv = 0.f;
        if (gnode < NN) {
            a = Ab[gnode * 8 + cc];
            beg = offs[gnode]; end = offs[gnode + 1];
            int deg = end - beg;
            inv = (deg > 0) ? 1.f / (float)deg : 0.f;
        }
        int f = 8 * cc;
        AsT[(f + 0) * AT + n] = bflo(a.x); AsT[(f + 1) * AT + n] = bfhi(a.x);
        AsT[(f + 2) * AT + n] = bflo(a.y); AsT[(f + 3) * AT + n] = bfhi(a.y);
        AsT[(f + 4) * AT + n] = bflo(a.z); AsT[(f + 5) * AT + n] = bfhi(a.z);
        AsT[(f + 6) * AT + n] = bflo(a.w); AsT[(f + 7) * AT + n] = bfhi(a.w);

#pragma unroll
        for (int half = 0; half < 2; ++half) {
            const int ch = half * 4 + c;            // table uint4 column this pass
            float s[8] = {0.f, 0.f, 0.f, 0.f, 0.f, 0.f, 0.f, 0.f};
            int j = beg;
            for (; j + 8 <= end; j += 8) {
                int v = csr[j + cc];                // 8 indices per group, 1 load/lane
                int e0 = __shfl(v, base + 4 * p + 0, 64);
                int e1 = __shfl(v, base + 4 * p + 1, 64);
                int e2 = __shfl(v, base + 4 * p + 2, 64);
                int e3 = __shfl(v, base + 4 * p + 3, 64);
                uint4 d0 = Ab[e0 * 8 + ch], d1 = Ab[e1 * 8 + ch];
                uint4 d2 = Ab[e2 * 8 + ch], d3 = Ab[e3 * 8 + ch];
                add8(s, d0); add8(s, d1); add8(s, d2); add8(s, d3);
            }
            int rem = end - j;
            if (rem > 0) {
                int v = csr[j + (cc < rem ? cc : 0)];
#pragma unroll
                for (int k = 0; k < 4; ++k) {
                    int ei = 4 * p + k;
                    int idx = __shfl(v, base + ei, 64);
                    if (ei < rem) { uint4 d = Ab[idx * 8 + ch]; add8(s, d); }
                }
            }
            // combine the two edge-parities (partner is in the same 8-lane group)
#pragma unroll
            for (int q = 0; q < 8; ++q) s[q] += __shfl_xor(s[q], 4, 64);
            if (p == 0) {
                int fb = ch * 8;
#pragma unroll
                for (int q = 0; q < 8; ++q) NsT[(fb + q) * AT + n] = s[q] * inv;
            }
        }
    }
    __syncthreads();

    // GEMM: 512 threads = 16(feat-grp) x 32(node-grp); microtile 2 nodes x 4 feats
    const int tx = tid & 15, ty = tid >> 4;
    float acc[2][4];
#pragma unroll
    for (int j = 0; j < 4; ++j) {
        float bv = b[4 * tx + j];
        acc[0][j] = bv; acc[1][j] = bv;
    }
#pragma unroll 4
    for (int k = 0; k < 64; ++k) {
        float2 a2 = *(const float2*)&AsT[k * AT + 2 * ty];
        float2 n2 = *(const float2*)&NsT[k * AT + 2 * ty];
        uint4 wq = *(const uint4*)&Wpk[k * 64 + 4 * tx];
        float ws_[4] = {bflo(wq.x), bflo(wq.y), bflo(wq.z), bflo(wq.w)};
        float wn_[4] = {bfhi(wq.x), bfhi(wq.y), bfhi(wq.z), bfhi(wq.w)};
        float a_[2] = {a2.x, a2.y};
        float n_[2] = {n2.x, n2.y};
#pragma unroll
        for (int i = 0; i < 2; ++i)
#pragma unroll
            for (int j = 0; j < 4; ++j)
                acc[i][j] += a_[i] * ws_[j] + n_[i] * wn_[j];
    }

    if (!LAST) {
#pragma unroll
        for (int i = 0; i < 2; ++i) {
            int node = node0 + 2 * ty + i;
            if (node < NN) {
                float o0 = acc[i][0] > 0.f ? acc[i][0] : 0.f;
                float o1 = acc[i][1] > 0.f ? acc[i][1] : 0.f;
                float o2 = acc[i][2] > 0.f ? acc[i][2] : 0.f;
                float o3 = acc[i][3] > 0.f ? acc[i][3] : 0.f;
                uint2 p;
                p.x = bf16rne(o0) | (bf16rne(o1) << 16);
                p.y = bf16rne(o2) | (bf16rne(o3) << 16);
                outb[node * 16 + tx] = p;
            }
        }
    } else {
        // fused final GEMM: h2 tile -> AsT transposed; Wfc (fp32) reuses Wpk storage
        __syncthreads();
        float* Wf = (float*)Wpk;
#pragma unroll
        for (int i = 0; i < 2; ++i)
#pragma unroll
            for (int j = 0; j < 4; ++j)
                AsT[(4 * tx + j) * AT + (2 * ty + i)] = acc[i][j];
        for (int i = tid; i < F * F / 4; i += 512)
            ((float4*)Wf)[i] = ((const float4*)Wfc)[i];
        __syncthreads();

        float acc2[2][4];
#pragma unroll
        for (int j = 0; j < 4; ++j) {
            float bv = bfc[4 * tx + j];
            acc2[0][j] = bv; acc2[1][j] = bv;
        }
#pragma unroll 4
        for (int k = 0; k < 64; ++k) {
            float2 a2 = *(const float2*)&AsT[k * AT + 2 * ty];
            float4 w4 = *(const float4*)&Wf[k * 64 + 4 * tx];
            float a_[2] = {a2.x, a2.y};
            float w_[4] = {w4.x, w4.y, w4.z, w4.w};
#pragma unroll
            for (int i = 0; i < 2; ++i)
#pragma unroll
                for (int j = 0; j < 4; ++j)
                    acc2[i][j] += a_[i] * w_[j];
        }
#pragma unroll
        for (int i = 0; i < 2; ++i) {
            int node = node0 + 2 * ty + i;
            if (node < NN) {
                float4 o;
                o.x = acc2[i][0]; o.y = acc2[i][1]; o.z = acc2[i][2]; o.w = acc2[i][3];
                *(float4*)&out[node * 64 + 4 * tx] = o;
            }
        }
    }
}

// ---------------- launch ----------------

extern "C" void kernel_launch(void* const* d_in, const int* in_sizes, int n_in,
                              void* d_out, int out_size, void* d_ws, size_t ws_size,
                              hipStream_t stream) {
    const float* embed = (const float*)d_in[0];
    const float* W1s = (const float*)d_in[1];
    const float* W1n = (const float*)d_in[2];
    const float* b1  = (const float*)d_in[3];
    const float* W2s = (const float*)d_in[4];
    const float* W2n = (const float*)d_in[5];
    const float* b2  = (const float*)d_in[6];
    const float* Wfc = (const float*)d_in[7];
    const float* bfc = (const float*)d_in[8];
    const int* ids = (const int*)d_in[9];
    const int* src = (const int*)d_in[10];
    const int* dst = (const int*)d_in[11];
    float* out = (float*)d_out;

    char* ws = (char*)d_ws;
    size_t off = 0;
    auto alloc = [&](size_t nb) {
        char* p = ws + off;
        off = (off + nb + 255) & ~(size_t)255;
        return p;
    };
    int*   cnt      = (int*)alloc(NN * sizeof(int));        // zeroed
    size_t zero_bytes = off;
    int*   offs     = (int*)alloc((NN + 1) * sizeof(int));
    int*   partials = (int*)alloc(SCAN_B * sizeof(int));
    int*   pos      = (int*)alloc(NE * sizeof(int));
    int*   csr      = (int*)alloc(NE * sizeof(int));
    uint2* xb       = (uint2*)alloc((size_t)NN * 16 * sizeof(uint2));  // bf16 x
    uint2* h1b      = (uint2*)alloc((size_t)NN * 16 * sizeof(uint2));  // bf16 h1

    hipMemsetAsync(d_ws, 0, zero_bytes, stream);

    const int TB = 256;
    const int EB = (NE + TB - 1) / TB;     // 3125
    k_count_gather<<<EB, TB, 0, stream>>>(dst, cnt, pos, embed, ids, xb);
    k_scan_a<<<SCAN_B, 256, 0, stream>>>(cnt, partials);
    k_scan_c2<<<SCAN_B, 256, 0, stream>>>(cnt, partials, offs);
    k_fill<<<EB, TB, 0, stream>>>(src, dst, offs, pos, csr);

    const int NB = (NN + 63) / 64;         // 782
    k_fused<false><<<NB, 512, 0, stream>>>((const uint4*)xb, offs, csr,
                                           W1s, W1n, b1, nullptr, nullptr,
                                           h1b, nullptr);
    k_fused<true><<<NB, 512, 0, stream>>>((const uint4*)h1b, offs, csr,
                                          W2s, W2n, b2, Wfc, bfc,
                                          nullptr, out);
}

// Round 11
// 230.289 us; speedup vs baseline: 1.0467x; 1.0467x over previous
//
#include <hip/hip_runtime.h>

#define NN 50000      // nodes
#define NE 800000     // edges
#define F  64         // feature dim
#define AT 68         // padded LDS stride (mult of 4, not mult of 32)
#define SCAN_B 49     // scan blocks: 49 * 1024 >= 50000

// bf16 round-to-nearest-even, returns low-16 bits
__device__ __forceinline__ unsigned bf16rne(float f) {
    unsigned u = __float_as_uint(f);
    return (u + 0x7fffu + ((u >> 16) & 1u)) >> 16;
}
__device__ __forceinline__ float bflo(unsigned p) { return __uint_as_float(p << 16); }
__device__ __forceinline__ float bfhi(unsigned p) { return __uint_as_float(p & 0xffff0000u); }

// ---------------- fused: edge degree count+slot  AND  embedding gather ----------------

__launch_bounds__(256)
__global__ void k_count_gather(const int* __restrict__ dst, int* __restrict__ cnt,
                               int* __restrict__ pos,
                               const float* __restrict__ embed, const int* __restrict__ ids,
                               uint2* __restrict__ xb) {
    int t = blockIdx.x * blockDim.x + threadIdx.x;
    if (t < NE) pos[t] = atomicAdd(&cnt[dst[t]], 1);   // coalesced pos write
    if (t < NN * 16) {
        int i = t >> 4, c = t & 15;
        float4 v = ((const float4*)embed)[ids[i] * 16 + c];
        uint2 p;
        p.x = bf16rne(v.x) | (bf16rne(v.y) << 16);
        p.y = bf16rne(v.z) | (bf16rne(v.w) << 16);
        xb[t] = p;
    }
}

// ---- 2-dispatch scan: block partials, then per-block redundant scan of partials ----

__launch_bounds__(256)
__global__ void k_scan_a(const int* __restrict__ cnt, int* __restrict__ partials) {
    __shared__ int sc[256];
    int t = threadIdx.x;
    int base = blockIdx.x * 1024 + t * 4;
    int s = 0;
#pragma unroll
    for (int k = 0; k < 4; ++k) {
        int idx = base + k;
        s += (idx < NN) ? cnt[idx] : 0;
    }
    sc[t] = s;
    __syncthreads();
    for (int d = 128; d > 0; d >>= 1) {
        if (t < d) sc[t] += sc[t + d];
        __syncthreads();
    }
    if (t == 0) partials[blockIdx.x] = sc[0];
}

__launch_bounds__(256)
__global__ void k_scan_c2(const int* __restrict__ cnt, const int* __restrict__ partials,
                          int* __restrict__ offs) {
    __shared__ int sboff;
    __shared__ int stotal;
    __shared__ int sc[256];
    int t = threadIdx.x;
    if (t < 64) {  // wave 0 redundantly scans the 49 partials
        int v = (t < SCAN_B) ? partials[t] : 0;
        int orig = v;
        for (int d = 1; d < 64; d <<= 1) {
            int u = __shfl_up(v, d);
            if (t >= d) v += u;
        }
        if (t == (int)blockIdx.x) sboff = v - orig;
        if (t == 63) stotal = v;
    }
    int base = blockIdx.x * 1024 + t * 4;
    int v4[4];
#pragma unroll
    for (int k = 0; k < 4; ++k) {
        int idx = base + k;
        v4[k] = (idx < NN) ? cnt[idx] : 0;
    }
    int lsum = v4[0] + v4[1] + v4[2] + v4[3];
    sc[t] = lsum;
    __syncthreads();
    for (int d = 1; d < 256; d <<= 1) {
        int u = (t >= d) ? sc[t - d] : 0;
        __syncthreads();
        sc[t] += u;
        __syncthreads();
    }
    int run = sboff + sc[t] - lsum;
#pragma unroll
    for (int k = 0; k < 4; ++k) {
        int idx = base + k;
        if (idx < NN) { offs[idx] = run; run += v4[k]; }
    }
    if (blockIdx.x == 0 && t == 0) offs[NN] = stotal;
}

// atomic-free fill: slot was precomputed in pos[]
__global__ void k_fill(const int* __restrict__ src, const int* __restrict__ dst,
                       const int* __restrict__ offs, const int* __restrict__ pos,
                       int* __restrict__ csr) {
    int e = blockIdx.x * blockDim.x + threadIdx.x;
    if (e < NE) csr[offs[dst[e]] + pos[e]] = src[e];
}

// ---------------- fused layer: aggregate + GEMM in one kernel ----------------
// 512 threads, 64 nodes/block. Agg phase: thread = (node, uint4 chunk), 8 lanes
// per node, unroll-8 full-row (128 B) gathers with shfl-broadcast indices;
// result -> NsT (fp32, no global round-trip). A-tile unpacked from the bf16
// table -> AsT. Weights Ws|Wn bf16-packed in one LDS array. LDS = 51.2 KB
// -> 3 blocks/CU. This is the measured-best structure (R9): the agg loop is
// throughput-bound on LLC random 128 B gathers (~2.5 TB/s effective); ILP
// deepening (R8) and feature-split locality (R10) both failed to beat it.
// LAST=false: relu -> bf16 out. LAST=true: second GEMM with Wfc/bfc -> fp32 out.

__device__ __forceinline__ void add8(float s[8], const uint4 v) {
    s[0] += bflo(v.x); s[1] += bfhi(v.x);
    s[2] += bflo(v.y); s[3] += bfhi(v.y);
    s[4] += bflo(v.z); s[5] += bfhi(v.z);
    s[6] += bflo(v.w); s[7] += bfhi(v.w);
}

template <bool LAST>
__launch_bounds__(512)
__global__ void k_fused(const uint4* __restrict__ Ab, const int* __restrict__ offs,
                        const int* __restrict__ csr,
                        const float* __restrict__ Ws, const float* __restrict__ Wn,
                        const float* __restrict__ b,
                        const float* __restrict__ Wfc, const float* __restrict__ bfc,
                        uint2* __restrict__ outb, float* __restrict__ out) {
    __shared__ alignas(16) float AsT[F * AT];      // self tile, transposed [f][node]
    __shared__ alignas(16) float NsT[F * AT];      // neighbor-mean tile, transposed
    __shared__ alignas(16) unsigned Wpk[F * F];    // Ws|Wn<<16 bf16-packed [k][f]

    const int tid = threadIdx.x;
    const int node0 = blockIdx.x * 64;

    // stage packed weights
    for (int i = tid; i < F * F; i += 512)
        Wpk[i] = bf16rne(Ws[i]) | (bf16rne(Wn[i]) << 16);

    // agg + A-stage: one (node, chunk) item per thread
    {
        const int n = tid >> 3;          // node within tile
        const int c = tid & 7;           // uint4 chunk (8 bf16 feats)
        const int lane = tid & 63;
        const int base = lane & 56;
        const int gnode = node0 + n;
        float s[8] = {0.f, 0.f, 0.f, 0.f, 0.f, 0.f, 0.f, 0.f};
        uint4 a = make_uint4(0u, 0u, 0u, 0u);
        float inv = 0.f;
        if (gnode < NN) {
            a = Ab[gnode * 8 + c];
            int beg = offs[gnode], end = offs[gnode + 1];
            int j = beg;
            for (; j + 8 <= end; j += 8) {
                int v = csr[j + c];
                int i0 = __shfl(v, base + 0, 64), i1 = __shfl(v, base + 1, 64);
                int i2 = __shfl(v, base + 2, 64), i3 = __shfl(v, base + 3, 64);
                int i4 = __shfl(v, base + 4, 64), i5 = __shfl(v, base + 5, 64);
                int i6 = __shfl(v, base + 6, 64), i7 = __shfl(v, base + 7, 64);
                uint4 d0 = Ab[i0 * 8 + c], d1 = Ab[i1 * 8 + c];
                uint4 d2 = Ab[i2 * 8 + c], d3 = Ab[i3 * 8 + c];
                uint4 d4 = Ab[i4 * 8 + c], d5 = Ab[i5 * 8 + c];
                uint4 d6 = Ab[i6 * 8 + c], d7 = Ab[i7 * 8 + c];
                add8(s, d0); add8(s, d1); add8(s, d2); add8(s, d3);
                add8(s, d4); add8(s, d5); add8(s, d6); add8(s, d7);
            }
            int rem = end - j;
            if (rem > 0) {
                int v = csr[j + (c < rem ? c : 0)];
                int idx[8];
#pragma unroll
                for (int k = 0; k < 8; ++k) idx[k] = __shfl(v, base + k, 64);
#pragma unroll
                for (int k = 0; k < 8; ++k)
                    if (k < rem) { uint4 d = Ab[idx[k] * 8 + c]; add8(s, d); }
            }
            int deg = end - beg;
            inv = (deg > 0) ? 1.f / (float)deg : 0.f;
        }
        int f = 8 * c;
        AsT[(f + 0) * AT + n] = bflo(a.x); AsT[(f + 1) * AT + n] = bfhi(a.x);
        AsT[(f + 2) * AT + n] = bflo(a.y); AsT[(f + 3) * AT + n] = bfhi(a.y);
        AsT[(f + 4) * AT + n] = bflo(a.z); AsT[(f + 5) * AT + n] = bfhi(a.z);
        AsT[(f + 6) * AT + n] = bflo(a.w); AsT[(f + 7) * AT + n] = bfhi(a.w);
#pragma unroll
        for (int q = 0; q < 8; ++q) NsT[(f + q) * AT + n] = s[q] * inv;
    }
    __syncthreads();

    // GEMM: 512 threads = 16(feat-grp) x 32(node-grp); microtile 2 nodes x 4 feats
    const int tx = tid & 15, ty = tid >> 4;
    float acc[2][4];
#pragma unroll
    for (int j = 0; j < 4; ++j) {
        float bv = b[4 * tx + j];
        acc[0][j] = bv; acc[1][j] = bv;
    }
#pragma unroll 4
    for (int k = 0; k < 64; ++k) {
        float2 a2 = *(const float2*)&AsT[k * AT + 2 * ty];
        float2 n2 = *(const float2*)&NsT[k * AT + 2 * ty];
        uint4 wq = *(const uint4*)&Wpk[k * 64 + 4 * tx];
        float ws_[4] = {bflo(wq.x), bflo(wq.y), bflo(wq.z), bflo(wq.w)};
        float wn_[4] = {bfhi(wq.x), bfhi(wq.y), bfhi(wq.z), bfhi(wq.w)};
        float a_[2] = {a2.x, a2.y};
        float n_[2] = {n2.x, n2.y};
#pragma unroll
        for (int i = 0; i < 2; ++i)
#pragma unroll
            for (int j = 0; j < 4; ++j)
                acc[i][j] += a_[i] * ws_[j] + n_[i] * wn_[j];
    }

    if (!LAST) {
#pragma unroll
        for (int i = 0; i < 2; ++i) {
            int node = node0 + 2 * ty + i;
            if (node < NN) {
                float o0 = acc[i][0] > 0.f ? acc[i][0] : 0.f;
                float o1 = acc[i][1] > 0.f ? acc[i][1] : 0.f;
                float o2 = acc[i][2] > 0.f ? acc[i][2] : 0.f;
                float o3 = acc[i][3] > 0.f ? acc[i][3] : 0.f;
                uint2 p;
                p.x = bf16rne(o0) | (bf16rne(o1) << 16);
                p.y = bf16rne(o2) | (bf16rne(o3) << 16);
                outb[node * 16 + tx] = p;
            }
        }
    } else {
        // fused final GEMM: h2 tile -> AsT transposed; Wfc (fp32) reuses Wpk storage
        __syncthreads();
        float* Wf = (float*)Wpk;
#pragma unroll
        for (int i = 0; i < 2; ++i)
#pragma unroll
            for (int j = 0; j < 4; ++j)
                AsT[(4 * tx + j) * AT + (2 * ty + i)] = acc[i][j];
        for (int i = tid; i < F * F / 4; i += 512)
            ((float4*)Wf)[i] = ((const float4*)Wfc)[i];
        __syncthreads();

        float acc2[2][4];
#pragma unroll
        for (int j = 0; j < 4; ++j) {
            float bv = bfc[4 * tx + j];
            acc2[0][j] = bv; acc2[1][j] = bv;
        }
#pragma unroll 4
        for (int k = 0; k < 64; ++k) {
            float2 a2 = *(const float2*)&AsT[k * AT + 2 * ty];
            float4 w4 = *(const float4*)&Wf[k * 64 + 4 * tx];
            float a_[2] = {a2.x, a2.y};
            float w_[4] = {w4.x, w4.y, w4.z, w4.w};
#pragma unroll
            for (int i = 0; i < 2; ++i)
#pragma unroll
                for (int j = 0; j < 4; ++j)
                    acc2[i][j] += a_[i] * w_[j];
        }
#pragma unroll
        for (int i = 0; i < 2; ++i) {
            int node = node0 + 2 * ty + i;
            if (node < NN) {
                float4 o;
                o.x = acc2[i][0]; o.y = acc2[i][1]; o.z = acc2[i][2]; o.w = acc2[i][3];
                *(float4*)&out[node * 64 + 4 * tx] = o;
            }
        }
    }
}

// ---------------- launch ----------------

extern "C" void kernel_launch(void* const* d_in, const int* in_sizes, int n_in,
                              void* d_out, int out_size, void* d_ws, size_t ws_size,
                              hipStream_t stream) {
    const float* embed = (const float*)d_in[0];
    const float* W1s = (const float*)d_in[1];
    const float* W1n = (const float*)d_in[2];
    const float* b1  = (const float*)d_in[3];
    const float* W2s = (const float*)d_in[4];
    const float* W2n = (const float*)d_in[5];
    const float* b2  = (const float*)d_in[6];
    const float* Wfc = (const float*)d_in[7];
    const float* bfc = (const float*)d_in[8];
    const int* ids = (const int*)d_in[9];
    const int* src = (const int*)d_in[10];
    const int* dst = (const int*)d_in[11];
    float* out = (float*)d_out;

    char* ws = (char*)d_ws;
    size_t off = 0;
    auto alloc = [&](size_t nb) {
        char* p = ws + off;
        off = (off + nb + 255) & ~(size_t)255;
        return p;
    };
    int*   cnt      = (int*)alloc(NN * sizeof(int));        // zeroed
    size_t zero_bytes = off;
    int*   offs     = (int*)alloc((NN + 1) * sizeof(int));
    int*   partials = (int*)alloc(SCAN_B * sizeof(int));
    int*   pos      = (int*)alloc(NE * sizeof(int));
    int*   csr      = (int*)alloc(NE * sizeof(int));
    uint2* xb       = (uint2*)alloc((size_t)NN * 16 * sizeof(uint2));  // bf16 x
    uint2* h1b      = (uint2*)alloc((size_t)NN * 16 * sizeof(uint2));  // bf16 h1

    hipMemsetAsync(d_ws, 0, zero_bytes, stream);

    const int TB = 256;
    const int EB = (NE + TB - 1) / TB;     // 3125
    k_count_gather<<<EB, TB, 0, stream>>>(dst, cnt, pos, embed, ids, xb);
    k_scan_a<<<SCAN_B, 256, 0, stream>>>(cnt, partials);
    k_scan_c2<<<SCAN_B, 256, 0, stream>>>(cnt, partials, offs);
    k_fill<<<EB, TB, 0, stream>>>(src, dst, offs, pos, csr);

    const int NB = (NN + 63) / 64;         // 782
    k_fused<false><<<NB, 512, 0, stream>>>((const uint4*)xb, offs, csr,
                                           W1s, W1n, b1, nullptr, nullptr,
                                           h1b, nullptr);
    k_fused<true><<<NB, 512, 0, stream>>>((const uint4*)h1b, offs, csr,
                                          W2s, W2n, b2, Wfc, bfc,
                                          nullptr, out);
}